// Round 7
// baseline (6306.046 us; speedup 1.0000x reference)
//
// ODE-RNN (B=128, F=512, I=128, H=512, O=1) on MI355X — Round 7.
// R6 (5.34 ms, exact) proved the same-XCD exchange. 5000 cy/stage remained:
// (a) central flag counter = 16 serialized same-line L2 RMWs (~1K cy);
// (b) producer epilogue = 256 scattered 2B stores/wave (1KB stride) ~ 4K cy
//     of L1-port txns.
// R7: (1) per-producer flag words (one relaxed atomic STORE each; consumers
//     poll 16 words = one coalesced line) — no RMW serialization;
// (2) MFMA operand-role swap: A/B frag layouts are lane-symmetric for
//     16x16x32, so mfma(W_frag, act_frag) computes D^T with the SAME
//     registers; lane then owns (1 sample x 4 consecutive cols) and the
//     epilogue is ONE 8B contiguous store (16 txns/wave, 16x fewer);
// (3) h32/fsum master copies become lane-private VGPRs (8 regs) — no LDS.
// Same-XCD cohorts, vmcnt-drain-before-signal, buffer_inv-before-gather all
// kept verbatim from R6 (proven). Predicted: 2.3-3.5 ms, absmax ~0.

#include <hip/hip_runtime.h>
#include <hip/hip_bf16.h>
#include <cstdint>
#include <cstddef>

#define HD 512
#define ID 128
#define FF 512
#define G 4          // groups (each owns 32 samples)
#define S 32         // samples per group
#define NBLK 16      // blocks per group (32-col weight shards)
#define AST 520      // LDS activation row stride (bf16 elems)
#define XST 136
#define NLAUNCH 256  // blocks launched (>= 9 complete cohorts by pigeonhole)

// ctl word offsets (all zeroed before seq_kernel)
#define CT_TICKET 0          // [16] per-XCD ticket counters
#define CT_CLAIM 16          // group claim counter
#define CT_TOTAL 17          // registered-block counter
#define CT_MAP 20            // [256] cohort -> group+1 (0 = unclaimed)
#define CT_PFLAG 288         // [G*16] per-producer stage flags (64B/group)
#define CT_WORDS (288 + G * 16)

typedef __bf16 bf16x8_t __attribute__((ext_vector_type(8)));
typedef unsigned short ushort8_t __attribute__((ext_vector_type(8)));
typedef unsigned short ushort4_t __attribute__((ext_vector_type(4)));
typedef float f32x4_t __attribute__((ext_vector_type(4)));

__device__ __forceinline__ unsigned short f2b(float x) {
  __hip_bfloat16 h = __float2bfloat16(x);
  return *reinterpret_cast<unsigned short*>(&h);
}
__device__ __forceinline__ bf16x8_t ld_frag(const unsigned short* p) {
  ushort8_t u = *reinterpret_cast<const ushort8_t*>(p);
  return __builtin_bit_cast(bf16x8_t, u);
}

// --- fp32 -> bf16 fragment-order pack (same layout as R3-R6) ---------------
// dst[i]: i = ((colt*KT + kt)*64 + lane)*8 + j, KT = Kd/32.
// lane = n + 16*kq holds W[colt*16+n][kt*32 + kq*8 + j].
__global__ void pack_kernel(const float* __restrict__ in,
                            unsigned short* __restrict__ out, int Kd) {
  int i = blockIdx.x * blockDim.x + threadIdx.x;
  int total = HD * Kd;
  if (i >= total) return;
  int KT = Kd >> 5;
  int j = i & 7;
  int lane = (i >> 3) & 63;
  int t = i >> 9;
  int kt = t % KT;
  int colt = t / KT;
  int n = lane & 15, kq = lane >> 4;
  out[i] = f2b(in[(size_t)(colt * 16 + n) * Kd + kt * 32 + kq * 8 + j]);
}

__global__ void zero_kernel(unsigned int* __restrict__ p, int n) {
  int i = blockIdx.x * blockDim.x + threadIdx.x;
  if (i < n) p[i] = 0u;
}

// acc += (Wshard-tile) @ (act-tile)^T, weights as A-operand (role swap:
// A/B frags are lane-symmetric, so register contents are unchanged).
// D: col(lane&15)=sample, row(kq*4+reg)=weight col within 16-tile.
template <int KT>
__device__ __forceinline__ f32x4_t mm_full(const bf16x8_t* wf,
                                           const unsigned short* arow,
                                           f32x4_t acc) {
#pragma unroll
  for (int kt = 0; kt < KT; ++kt) {
    bf16x8_t a = ld_frag(arow + kt * 32);
    acc = __builtin_amdgcn_mfma_f32_16x16x32_bf16(wf[kt], a, acc, 0, 0, 0);
  }
  return acc;
}

// --- the sequential recurrence ---------------------------------------------
__global__ __launch_bounds__(256, 1) void seq_kernel(
    const float* __restrict__ x, const float* __restrict__ tp,
    const float* __restrict__ b1, const float* __restrict__ b2,
    const float* __restrict__ bih, const float* __restrict__ bhh,
    const float* __restrict__ Wc,
    const unsigned short* __restrict__ W1p, const unsigned short* __restrict__ W2p,
    const unsigned short* __restrict__ Whhp, const unsigned short* __restrict__ Wihp,
    unsigned short* __restrict__ actg,   // G * 2 * S*512 bf16 exchange regions
    unsigned int* __restrict__ ctl,      // control words (see CT_*)
    float* __restrict__ logits) {        // 128 fp32, pre-zeroed
  __shared__ __align__(16) unsigned short actb[S][AST];  // full activation
  __shared__ __align__(16) unsigned short xb[S][XST];    // x_t
  __shared__ float scale[S];     // dt per sample
  __shared__ float redl[S][2];
  __shared__ int role[2];

  const int tid = threadIdx.x;

  // ---- XCD-aware registration & group claiming (tid 0 only; R5/R6-proven) --
  if (tid == 0) {
    unsigned xcc;
    asm volatile("s_getreg_b32 %0, hwreg(HW_REG_XCC_ID, 0, 32)" : "=s"(xcc));
    const int xcd = (int)(xcc & 15u);
    unsigned rank = __hip_atomic_fetch_add(&ctl[CT_TICKET + xcd], 1u,
                                           __ATOMIC_RELAXED,
                                           __HIP_MEMORY_SCOPE_AGENT);
    const unsigned slot = (unsigned)xcd * 16u + (rank >> 4);
    if ((rank & 15u) == 15u) {  // cohort completer claims a group id
      unsigned gg = __hip_atomic_fetch_add(&ctl[CT_CLAIM], 1u,
                                           __ATOMIC_RELAXED,
                                           __HIP_MEMORY_SCOPE_AGENT);
      __hip_atomic_store(&ctl[CT_MAP + slot], gg + 1u, __ATOMIC_RELAXED,
                         __HIP_MEMORY_SCOPE_AGENT);
      asm volatile("s_waitcnt vmcnt(0)" ::: "memory");  // publish before total
    }
    __hip_atomic_fetch_add(&ctl[CT_TOTAL], 1u, __ATOMIC_RELAXED,
                           __HIP_MEMORY_SCOPE_AGENT);
    unsigned m;
    for (;;) {
      m = __hip_atomic_load(&ctl[CT_MAP + slot], __ATOMIC_RELAXED,
                            __HIP_MEMORY_SCOPE_AGENT);
      if (m) break;
      if (__hip_atomic_load(&ctl[CT_TOTAL], __ATOMIC_RELAXED,
                            __HIP_MEMORY_SCOPE_AGENT) >= (unsigned)NLAUNCH) {
        m = __hip_atomic_load(&ctl[CT_MAP + slot], __ATOMIC_RELAXED,
                              __HIP_MEMORY_SCOPE_AGENT);
        break;
      }
      __builtin_amdgcn_s_sleep(2);
    }
    role[0] = (m == 0 || m > (unsigned)G) ? -1 : (int)(m - 1);
    role[1] = (int)(rank & 15u);
  }
  __syncthreads();
  if (role[0] < 0) return;   // surplus / incomplete cohort: exit
  const int g = role[0];     // group id 0..3  (samples [g*32, g*32+32))
  const int j = role[1];     // 32-col weight shard 0..15

  const int wave = tid >> 6;
  const int lane = tid & 63;
  const int n = lane & 15;
  const int kq = lane >> 4;
  const int ct = wave & 1;         // col-tile within shard
  const int rt = wave >> 1;        // row-tile (samples)
  const int colt = j * 2 + ct;     // global 16-col tile
  const int sl2 = rt * 16 + n;     // this lane's sample (D col = lane&15)
  const int gc0 = j * 32 + ct * 16 + kq * 4;  // lane's 4-col base (D rows)
  const int s0 = g * S;

  // ---- weights into registers: 208 VGPR/lane of frags ----
  bf16x8_t w1f[16], w2f[16], whhf[16], wihf[4];
#pragma unroll
  for (int kt = 0; kt < 16; ++kt) {
    w1f[kt]  = ld_frag(W1p  + (size_t)(colt * 16 + kt) * 512 + lane * 8);
    w2f[kt]  = ld_frag(W2p  + (size_t)(colt * 16 + kt) * 512 + lane * 8);
    whhf[kt] = ld_frag(Whhp + (size_t)(colt * 16 + kt) * 512 + lane * 8);
  }
#pragma unroll
  for (int kt = 0; kt < 4; ++kt)
    wihf[kt] = ld_frag(Wihp + (size_t)(colt * 4 + kt) * 512 + lane * 8);

  // per-lane 4-col bias vectors and lane-private fp32 state
  const f32x4_t b1v = *reinterpret_cast<const f32x4_t*>(&b1[gc0]);
  const f32x4_t b2v = *reinterpret_cast<const f32x4_t*>(&b2[gc0]);
  f32x4_t bbv;
#pragma unroll
  for (int r_ = 0; r_ < 4; ++r_) bbv[r_] = bih[gc0 + r_] + bhh[gc0 + r_];
  f32x4_t hv = {0.f, 0.f, 0.f, 0.f};   // fp32 master h (lane-private)
  f32x4_t fsv = {0.f, 0.f, 0.f, 0.f};  // sum of post-RNN h (lane-private)

  for (int i = tid; i < S * AST; i += 256) (&actb[0][0])[i] = 0;
  __syncthreads();

  unsigned short* const myact = actg + (size_t)g * (2 * S * 512);
  unsigned int* const pf = &ctl[CT_PFLAG + g * 16];
  int bar = 0;

  // Same-XCD exchange barrier + gather (R6-proven ordering):
  // per-wave vmcnt(0) drain -> sync -> per-producer flag STORE (no RMW) ->
  // wave0 polls all 16 flag words (one coalesced line) -> sync ->
  // buffer_inv (drop stale L1) -> plain 16B gathers from local L2 -> LDS.
  auto xbar = [&]() {
    asm volatile("s_waitcnt vmcnt(0)" ::: "memory");
    __syncthreads();
    const unsigned want = (unsigned)(bar + 1);
    if (tid == 0)
      __hip_atomic_store(&pf[j], want, __ATOMIC_RELAXED,
                         __HIP_MEMORY_SCOPE_AGENT);
    if (tid < 64) {
      unsigned v;
      do {
        v = __hip_atomic_load(&pf[tid & 15], __ATOMIC_RELAXED,
                              __HIP_MEMORY_SCOPE_AGENT);
      } while (__ballot(v < want) != 0ull);
    }
    __syncthreads();
    asm volatile("buffer_inv" ::: "memory");
    asm volatile("s_waitcnt vmcnt(0)" ::: "memory");
    const ushort8_t* src =
        (const ushort8_t*)(myact + (size_t)(bar & 1) * (S * 512));
    ushort8_t v[8];
#pragma unroll
    for (int rd = 0; rd < 8; ++rd) v[rd] = src[tid + rd * 256];
#pragma unroll
    for (int rd = 0; rd < 8; ++rd) {
      int c = tid + rd * 256;  // ushort8 unit index over [S][512]
      *reinterpret_cast<ushort8_t*>(&actb[c >> 6][(c & 63) * 8]) = v[rd];
    }
    __syncthreads();
    ++bar;
  };

#pragma unroll 1
  for (int f = 0; f < FF; ++f) {
    // stage x_t (bf16) and dt
    for (int i = tid; i < S * ID; i += 256) {
      int s = i >> 7, ii = i & (ID - 1);
      xb[s][ii] = f2b(x[((size_t)(s0 + s) * FF + f) * ID + ii]);
    }
    if (tid < S) {
      float d = (f > 0) ? (tp[(size_t)(s0 + tid) * FF + f] -
                           tp[(size_t)(s0 + tid) * FF + f - 1])
                        : 0.f;
      scale[tid] = d;
    }
    __syncthreads();

    const unsigned short* arow = &actb[sl2][kq * 8];
    const unsigned short* xrow = &xb[sl2][kq * 8];
    unsigned short* const dst0 = myact;     // buffer parity applied per stage

    // ---- A: g = relu(h @ W1^T + b1) ----
    {
      f32x4_t acc = {0.f, 0.f, 0.f, 0.f};
      acc = mm_full<16>(w1f, arow, acc);
      unsigned short* dst = dst0 + (size_t)(bar & 1) * (S * 512);
      ushort4_t o;
#pragma unroll
      for (int r_ = 0; r_ < 4; ++r_) {
        float y = acc[r_] + b1v[r_];
        o[r_] = f2b(y > 0.f ? y : 0.f);
      }
      *reinterpret_cast<ushort4_t*>(dst + (size_t)sl2 * 512 + gc0) = o;
      xbar();
    }
    // ---- B: k1 = g @ W2^T + b2; publish h+0.8dt k1; hv += 0.5dt k1 ----
    {
      f32x4_t acc = {0.f, 0.f, 0.f, 0.f};
      acc = mm_full<16>(w2f, arow, acc);
      unsigned short* dst = dst0 + (size_t)(bar & 1) * (S * 512);
      const float d = scale[sl2];
      ushort4_t o;
#pragma unroll
      for (int r_ = 0; r_ < 4; ++r_) {
        float k1 = acc[r_] + b2v[r_];
        float ho = hv[r_];
        o[r_] = f2b(ho + 0.8f * d * k1);
        hv[r_] = ho + 0.5f * d * k1;
      }
      *reinterpret_cast<ushort4_t*>(dst + (size_t)sl2 * 512 + gc0) = o;
      xbar();
    }
    // ---- C: g2 = relu(hb2 @ W1^T + b1) ----
    {
      f32x4_t acc = {0.f, 0.f, 0.f, 0.f};
      acc = mm_full<16>(w1f, arow, acc);
      unsigned short* dst = dst0 + (size_t)(bar & 1) * (S * 512);
      ushort4_t o;
#pragma unroll
      for (int r_ = 0; r_ < 4; ++r_) {
        float y = acc[r_] + b1v[r_];
        o[r_] = f2b(y > 0.f ? y : 0.f);
      }
      *reinterpret_cast<ushort4_t*>(dst + (size_t)sl2 * 512 + gc0) = o;
      xbar();
    }
    // ---- D: k2 = g2 @ W2^T + b2; h = hv + 0.5dt k2; publish h ----
    {
      f32x4_t acc = {0.f, 0.f, 0.f, 0.f};
      acc = mm_full<16>(w2f, arow, acc);
      unsigned short* dst = dst0 + (size_t)(bar & 1) * (S * 512);
      const float d = scale[sl2];
      ushort4_t o;
#pragma unroll
      for (int r_ = 0; r_ < 4; ++r_) {
        float h = hv[r_] + 0.5f * d * (acc[r_] + b2v[r_]);
        hv[r_] = h;
        o[r_] = f2b(h);
      }
      *reinterpret_cast<ushort4_t*>(dst + (size_t)sl2 * 512 + gc0) = o;
      xbar();
    }
    // ---- RNN: h = tanh(x @ Wih^T + h' @ Whh^T + bih + bhh) ----
    {
      f32x4_t acc = {0.f, 0.f, 0.f, 0.f};
      acc = mm_full<4>(wihf, xrow, acc);
      acc = mm_full<16>(whhf, arow, acc);
      unsigned short* dst = dst0 + (size_t)(bar & 1) * (S * 512);
      ushort4_t o;
#pragma unroll
      for (int r_ = 0; r_ < 4; ++r_) {
        float t = tanhf(acc[r_] + bbv[r_]);
        hv[r_] = t;
        fsv[r_] += t;
        o[r_] = f2b(t);
      }
      *reinterpret_cast<ushort4_t*>(dst + (size_t)sl2 * 512 + gc0) = o;
      xbar();
    }
  }

  // ---- classifier: logits[s] += sum over this block's 32 cols ----
  {
    float p = fsv[0] * Wc[gc0] + fsv[1] * Wc[gc0 + 1] +
              fsv[2] * Wc[gc0 + 2] + fsv[3] * Wc[gc0 + 3];
    p += __shfl_xor(p, 16, 64);   // reduce over kq
    p += __shfl_xor(p, 32, 64);
    if (lane < 16) redl[rt * 16 + lane][ct] = p;
  }
  __syncthreads();
  if (tid < S) {
    float v = redl[tid][0] + redl[tid][1];
    atomicAdd(&logits[s0 + tid], v);   // device-scope, cross-XCD safe
  }
}

__global__ void fin_kernel(const float* __restrict__ logits,
                           const float* __restrict__ bc,
                           float* __restrict__ out) {
  int b = threadIdx.x;
  if (b < 128) out[b] = 1.f / (1.f + __expf(-(logits[b] * (1.f / FF) + bc[0])));
}

// --- launch -----------------------------------------------------------------
extern "C" void kernel_launch(void* const* d_in, const int* in_sizes, int n_in,
                              void* d_out, int out_size, void* d_ws, size_t ws_size,
                              hipStream_t stream) {
  const float* x   = (const float*)d_in[0];
  const float* tp  = (const float*)d_in[1];
  const float* W1  = (const float*)d_in[2];
  const float* b1  = (const float*)d_in[3];
  const float* W2  = (const float*)d_in[4];
  const float* b2  = (const float*)d_in[5];
  const float* Wih = (const float*)d_in[6];
  const float* Whh = (const float*)d_in[7];
  const float* bih = (const float*)d_in[8];
  const float* bhh = (const float*)d_in[9];
  const float* Wc  = (const float*)d_in[10];
  const float* bc  = (const float*)d_in[11];
  float* out = (float*)d_out;

  unsigned short* W1p  = (unsigned short*)d_ws;
  unsigned short* W2p  = W1p + (size_t)HD * HD;
  unsigned short* Whhp = W2p + (size_t)HD * HD;
  unsigned short* Wihp = Whhp + (size_t)HD * HD;
  unsigned short* actg = Wihp + (size_t)HD * ID;           // G*2*S*512 bf16
  unsigned int*   ctl  = (unsigned int*)(actg + (size_t)G * 2 * S * 512);
  float*          logits = (float*)(ctl + CT_WORDS);
  // total ws use ~2.0 MB

  pack_kernel<<<(HD * HD + 255) / 256, 256, 0, stream>>>(W1, W1p, HD);
  pack_kernel<<<(HD * HD + 255) / 256, 256, 0, stream>>>(W2, W2p, HD);
  pack_kernel<<<(HD * HD + 255) / 256, 256, 0, stream>>>(Whh, Whhp, HD);
  pack_kernel<<<(HD * ID + 255) / 256, 256, 0, stream>>>(Wih, Wihp, ID);
  int nz = CT_WORDS + 128;  // ctl + logits
  zero_kernel<<<(nz + 255) / 256, 256, 0, stream>>>(ctl, nz);

  seq_kernel<<<dim3(NLAUNCH), dim3(256), 0, stream>>>(
      x, tp, b1, b2, bih, bhh, Wc, W1p, W2p, Whhp, Wihp, actg, ctl, logits);
  fin_kernel<<<dim3(1), dim3(128), 0, stream>>>(logits, bc, out);
}

// Round 8
// 6124.217 us; speedup vs baseline: 1.0297x; 1.0297x over previous
//
// ODE-RNN (B=128, F=512, I=128, H=512, O=1) on MI355X — Round 8.
// R7 post-mortem: removing flag-RMW serialization + scattered stores changed
// nothing (6.3 vs 5.3 ms) => the wall is the signal/poll path: agent-scope
// atomics execute at the MALL (device coherence point), ~600-900 cy per round
// trip, x 16 blocks polling one line. R6 proved plain stores + buffer_inv +
// plain loads are coherent WITHIN an XCD at local-L2 latency (~200 cy) — so
// R8 moves the FLAGS onto that same path:
//   - producer: plain volatile flag store AFTER per-wave vmcnt(0) drain +
//     block sync (data provably in L2 before flag can land in L2);
//   - consumer: 16-lane poll loop, each iter = buffer_inv + plain volatile
//     load of the 16 flag words (one local-L2 line);
//   - per-group flag lines padded to 256 B so no line is plain-written by
//     two XCDs (dirty-line writeback aliasing).
// Cohort formation (agent atomics, one-time), double-buffered exchange,
// gather+LDS, register-resident weights: verbatim from R6/R7 (proven).
// Numerics identical (absmax 0 in R6/R7). Predicted: 2.2-3.2 ms.

#include <hip/hip_runtime.h>
#include <hip/hip_bf16.h>
#include <cstdint>
#include <cstddef>

#define HD 512
#define ID 128
#define FF 512
#define G 4          // groups (each owns 32 samples)
#define S 32         // samples per group
#define NBLK 16      // blocks per group (32-col weight shards)
#define AST 520      // LDS activation row stride (bf16 elems)
#define XST 136
#define NLAUNCH 256  // blocks launched (>= 9 complete cohorts by pigeonhole)

// ctl word offsets (all zeroed before seq_kernel)
#define CT_TICKET 0          // [16] per-XCD ticket counters
#define CT_CLAIM 16          // group claim counter
#define CT_TOTAL 17          // registered-block counter
#define CT_MAP 20            // [256] cohort -> group+1 (0 = unclaimed)
#define CT_PFLAG 512         // [G*64] per-producer stage flags, 256B/group
#define CT_WORDS (512 + G * 64)

typedef __bf16 bf16x8_t __attribute__((ext_vector_type(8)));
typedef unsigned short ushort8_t __attribute__((ext_vector_type(8)));
typedef unsigned short ushort4_t __attribute__((ext_vector_type(4)));
typedef float f32x4_t __attribute__((ext_vector_type(4)));

__device__ __forceinline__ unsigned short f2b(float x) {
  __hip_bfloat16 h = __float2bfloat16(x);
  return *reinterpret_cast<unsigned short*>(&h);
}
__device__ __forceinline__ bf16x8_t ld_frag(const unsigned short* p) {
  ushort8_t u = *reinterpret_cast<const ushort8_t*>(p);
  return __builtin_bit_cast(bf16x8_t, u);
}

// --- fp32 -> bf16 fragment-order pack (same layout as R3-R7) ---------------
// dst[i]: i = ((colt*KT + kt)*64 + lane)*8 + j, KT = Kd/32.
// lane = n + 16*kq holds W[colt*16+n][kt*32 + kq*8 + j].
__global__ void pack_kernel(const float* __restrict__ in,
                            unsigned short* __restrict__ out, int Kd) {
  int i = blockIdx.x * blockDim.x + threadIdx.x;
  int total = HD * Kd;
  if (i >= total) return;
  int KT = Kd >> 5;
  int j = i & 7;
  int lane = (i >> 3) & 63;
  int t = i >> 9;
  int kt = t % KT;
  int colt = t / KT;
  int n = lane & 15, kq = lane >> 4;
  out[i] = f2b(in[(size_t)(colt * 16 + n) * Kd + kt * 32 + kq * 8 + j]);
}

__global__ void zero_kernel(unsigned int* __restrict__ p, int n) {
  int i = blockIdx.x * blockDim.x + threadIdx.x;
  if (i < n) p[i] = 0u;
}

// acc += (Wshard-tile) @ (act-tile)^T, weights as A-operand.
// D: col(lane&15)=sample, row(kq*4+reg)=weight col within 16-tile.
template <int KT>
__device__ __forceinline__ f32x4_t mm_full(const bf16x8_t* wf,
                                           const unsigned short* arow,
                                           f32x4_t acc) {
#pragma unroll
  for (int kt = 0; kt < KT; ++kt) {
    bf16x8_t a = ld_frag(arow + kt * 32);
    acc = __builtin_amdgcn_mfma_f32_16x16x32_bf16(wf[kt], a, acc, 0, 0, 0);
  }
  return acc;
}

// --- the sequential recurrence ---------------------------------------------
__global__ __launch_bounds__(256, 1) void seq_kernel(
    const float* __restrict__ x, const float* __restrict__ tp,
    const float* __restrict__ b1, const float* __restrict__ b2,
    const float* __restrict__ bih, const float* __restrict__ bhh,
    const float* __restrict__ Wc,
    const unsigned short* __restrict__ W1p, const unsigned short* __restrict__ W2p,
    const unsigned short* __restrict__ Whhp, const unsigned short* __restrict__ Wihp,
    unsigned short* __restrict__ actg,   // G * 2 * S*512 bf16 exchange regions
    unsigned int* __restrict__ ctl,      // control words (see CT_*)
    float* __restrict__ logits) {        // 128 fp32, pre-zeroed
  __shared__ __align__(16) unsigned short actb[S][AST];  // full activation
  __shared__ __align__(16) unsigned short xb[S][XST];    // x_t
  __shared__ float scale[S];     // dt per sample
  __shared__ float redl[S][2];
  __shared__ int role[2];

  const int tid = threadIdx.x;

  // ---- XCD-aware registration & group claiming (tid 0 only; R5-R7 proven) --
  if (tid == 0) {
    unsigned xcc;
    asm volatile("s_getreg_b32 %0, hwreg(HW_REG_XCC_ID, 0, 32)" : "=s"(xcc));
    const int xcd = (int)(xcc & 15u);
    unsigned rank = __hip_atomic_fetch_add(&ctl[CT_TICKET + xcd], 1u,
                                           __ATOMIC_RELAXED,
                                           __HIP_MEMORY_SCOPE_AGENT);
    const unsigned slot = (unsigned)xcd * 16u + (rank >> 4);
    if ((rank & 15u) == 15u) {  // cohort completer claims a group id
      unsigned gg = __hip_atomic_fetch_add(&ctl[CT_CLAIM], 1u,
                                           __ATOMIC_RELAXED,
                                           __HIP_MEMORY_SCOPE_AGENT);
      __hip_atomic_store(&ctl[CT_MAP + slot], gg + 1u, __ATOMIC_RELAXED,
                         __HIP_MEMORY_SCOPE_AGENT);
      asm volatile("s_waitcnt vmcnt(0)" ::: "memory");  // publish before total
    }
    __hip_atomic_fetch_add(&ctl[CT_TOTAL], 1u, __ATOMIC_RELAXED,
                           __HIP_MEMORY_SCOPE_AGENT);
    unsigned m;
    for (;;) {
      m = __hip_atomic_load(&ctl[CT_MAP + slot], __ATOMIC_RELAXED,
                            __HIP_MEMORY_SCOPE_AGENT);
      if (m) break;
      if (__hip_atomic_load(&ctl[CT_TOTAL], __ATOMIC_RELAXED,
                            __HIP_MEMORY_SCOPE_AGENT) >= (unsigned)NLAUNCH) {
        m = __hip_atomic_load(&ctl[CT_MAP + slot], __ATOMIC_RELAXED,
                              __HIP_MEMORY_SCOPE_AGENT);
        break;
      }
      __builtin_amdgcn_s_sleep(2);
    }
    role[0] = (m == 0 || m > (unsigned)G) ? -1 : (int)(m - 1);
    role[1] = (int)(rank & 15u);
  }
  __syncthreads();
  if (role[0] < 0) return;   // surplus / incomplete cohort: exit
  const int g = role[0];     // group id 0..3  (samples [g*32, g*32+32))
  const int j = role[1];     // 32-col weight shard 0..15

  const int wave = tid >> 6;
  const int lane = tid & 63;
  const int n = lane & 15;
  const int kq = lane >> 4;
  const int ct = wave & 1;         // col-tile within shard
  const int rt = wave >> 1;        // row-tile (samples)
  const int colt = j * 2 + ct;     // global 16-col tile
  const int sl2 = rt * 16 + n;     // this lane's sample (D col = lane&15)
  const int gc0 = j * 32 + ct * 16 + kq * 4;  // lane's 4-col base (D rows)
  const int s0 = g * S;

  // ---- weights into registers: 208 VGPR/lane of frags ----
  bf16x8_t w1f[16], w2f[16], whhf[16], wihf[4];
#pragma unroll
  for (int kt = 0; kt < 16; ++kt) {
    w1f[kt]  = ld_frag(W1p  + (size_t)(colt * 16 + kt) * 512 + lane * 8);
    w2f[kt]  = ld_frag(W2p  + (size_t)(colt * 16 + kt) * 512 + lane * 8);
    whhf[kt] = ld_frag(Whhp + (size_t)(colt * 16 + kt) * 512 + lane * 8);
  }
#pragma unroll
  for (int kt = 0; kt < 4; ++kt)
    wihf[kt] = ld_frag(Wihp + (size_t)(colt * 4 + kt) * 512 + lane * 8);

  // per-lane 4-col bias vectors and lane-private fp32 state
  const f32x4_t b1v = *reinterpret_cast<const f32x4_t*>(&b1[gc0]);
  const f32x4_t b2v = *reinterpret_cast<const f32x4_t*>(&b2[gc0]);
  f32x4_t bbv;
#pragma unroll
  for (int r_ = 0; r_ < 4; ++r_) bbv[r_] = bih[gc0 + r_] + bhh[gc0 + r_];
  f32x4_t hv = {0.f, 0.f, 0.f, 0.f};   // fp32 master h (lane-private)
  f32x4_t fsv = {0.f, 0.f, 0.f, 0.f};  // sum of post-RNN h (lane-private)

  for (int i = tid; i < S * AST; i += 256) (&actb[0][0])[i] = 0;
  __syncthreads();

  unsigned short* const myact = actg + (size_t)g * (2 * S * 512);
  unsigned int* const pf = &ctl[CT_PFLAG + g * 64];  // 16 words, own 256B
  int bar = 0;

  // Same-XCD exchange barrier + gather, all on the PLAIN/local-L2 path:
  // per-wave vmcnt(0) drain -> sync -> plain volatile flag store (stage#) ->
  // 16-lane poll: { buffer_inv; plain volatile load; } until all >= want ->
  // sync -> buffer_inv -> plain 16B gathers from local L2 -> LDS -> sync.
  auto xbar = [&]() {
    asm volatile("s_waitcnt vmcnt(0)" ::: "memory");
    __syncthreads();
    const unsigned want = (unsigned)(bar + 1);
    if (tid == 0)
      *(volatile unsigned int*)(pf + j) = want;
    if (tid < 16) {
      for (;;) {
        asm volatile("buffer_inv" ::: "memory");
        unsigned v = *(volatile const unsigned int*)(pf + tid);
        if (__ballot(v < want) == 0ull) break;
      }
    }
    __syncthreads();
    asm volatile("buffer_inv" ::: "memory");
    asm volatile("s_waitcnt vmcnt(0)" ::: "memory");
    const ushort8_t* src =
        (const ushort8_t*)(myact + (size_t)(bar & 1) * (S * 512));
    ushort8_t v[8];
#pragma unroll
    for (int rd = 0; rd < 8; ++rd) v[rd] = src[tid + rd * 256];
#pragma unroll
    for (int rd = 0; rd < 8; ++rd) {
      int c = tid + rd * 256;  // ushort8 unit index over [S][512]
      *reinterpret_cast<ushort8_t*>(&actb[c >> 6][(c & 63) * 8]) = v[rd];
    }
    __syncthreads();
    ++bar;
  };

#pragma unroll 1
  for (int f = 0; f < FF; ++f) {
    // stage x_t (bf16) and dt
    for (int i = tid; i < S * ID; i += 256) {
      int s = i >> 7, ii = i & (ID - 1);
      xb[s][ii] = f2b(x[((size_t)(s0 + s) * FF + f) * ID + ii]);
    }
    if (tid < S) {
      float d = (f > 0) ? (tp[(size_t)(s0 + tid) * FF + f] -
                           tp[(size_t)(s0 + tid) * FF + f - 1])
                        : 0.f;
      scale[tid] = d;
    }
    __syncthreads();

    const unsigned short* arow = &actb[sl2][kq * 8];
    const unsigned short* xrow = &xb[sl2][kq * 8];
    unsigned short* const dst0 = myact;     // buffer parity applied per stage

    // ---- A: g = relu(h @ W1^T + b1) ----
    {
      f32x4_t acc = {0.f, 0.f, 0.f, 0.f};
      acc = mm_full<16>(w1f, arow, acc);
      unsigned short* dst = dst0 + (size_t)(bar & 1) * (S * 512);
      ushort4_t o;
#pragma unroll
      for (int r_ = 0; r_ < 4; ++r_) {
        float y = acc[r_] + b1v[r_];
        o[r_] = f2b(y > 0.f ? y : 0.f);
      }
      *reinterpret_cast<ushort4_t*>(dst + (size_t)sl2 * 512 + gc0) = o;
      xbar();
    }
    // ---- B: k1 = g @ W2^T + b2; publish h+0.8dt k1; hv += 0.5dt k1 ----
    {
      f32x4_t acc = {0.f, 0.f, 0.f, 0.f};
      acc = mm_full<16>(w2f, arow, acc);
      unsigned short* dst = dst0 + (size_t)(bar & 1) * (S * 512);
      const float d = scale[sl2];
      ushort4_t o;
#pragma unroll
      for (int r_ = 0; r_ < 4; ++r_) {
        float k1 = acc[r_] + b2v[r_];
        float ho = hv[r_];
        o[r_] = f2b(ho + 0.8f * d * k1);
        hv[r_] = ho + 0.5f * d * k1;
      }
      *reinterpret_cast<ushort4_t*>(dst + (size_t)sl2 * 512 + gc0) = o;
      xbar();
    }
    // ---- C: g2 = relu(hb2 @ W1^T + b1) ----
    {
      f32x4_t acc = {0.f, 0.f, 0.f, 0.f};
      acc = mm_full<16>(w1f, arow, acc);
      unsigned short* dst = dst0 + (size_t)(bar & 1) * (S * 512);
      ushort4_t o;
#pragma unroll
      for (int r_ = 0; r_ < 4; ++r_) {
        float y = acc[r_] + b1v[r_];
        o[r_] = f2b(y > 0.f ? y : 0.f);
      }
      *reinterpret_cast<ushort4_t*>(dst + (size_t)sl2 * 512 + gc0) = o;
      xbar();
    }
    // ---- D: k2 = g2 @ W2^T + b2; h = hv + 0.5dt k2; publish h ----
    {
      f32x4_t acc = {0.f, 0.f, 0.f, 0.f};
      acc = mm_full<16>(w2f, arow, acc);
      unsigned short* dst = dst0 + (size_t)(bar & 1) * (S * 512);
      const float d = scale[sl2];
      ushort4_t o;
#pragma unroll
      for (int r_ = 0; r_ < 4; ++r_) {
        float h = hv[r_] + 0.5f * d * (acc[r_] + b2v[r_]);
        hv[r_] = h;
        o[r_] = f2b(h);
      }
      *reinterpret_cast<ushort4_t*>(dst + (size_t)sl2 * 512 + gc0) = o;
      xbar();
    }
    // ---- RNN: h = tanh(x @ Wih^T + h' @ Whh^T + bih + bhh) ----
    {
      f32x4_t acc = {0.f, 0.f, 0.f, 0.f};
      acc = mm_full<4>(wihf, xrow, acc);
      acc = mm_full<16>(whhf, arow, acc);
      unsigned short* dst = dst0 + (size_t)(bar & 1) * (S * 512);
      ushort4_t o;
#pragma unroll
      for (int r_ = 0; r_ < 4; ++r_) {
        float t = tanhf(acc[r_] + bbv[r_]);
        hv[r_] = t;
        fsv[r_] += t;
        o[r_] = f2b(t);
      }
      *reinterpret_cast<ushort4_t*>(dst + (size_t)sl2 * 512 + gc0) = o;
      xbar();
    }
  }

  // ---- classifier: logits[s] += sum over this block's 32 cols ----
  {
    float p = fsv[0] * Wc[gc0] + fsv[1] * Wc[gc0 + 1] +
              fsv[2] * Wc[gc0 + 2] + fsv[3] * Wc[gc0 + 3];
    p += __shfl_xor(p, 16, 64);   // reduce over kq
    p += __shfl_xor(p, 32, 64);
    if (lane < 16) redl[rt * 16 + lane][ct] = p;
  }
  __syncthreads();
  if (tid < S) {
    float v = redl[tid][0] + redl[tid][1];
    atomicAdd(&logits[s0 + tid], v);   // device-scope, cross-XCD safe
  }
}

__global__ void fin_kernel(const float* __restrict__ logits,
                           const float* __restrict__ bc,
                           float* __restrict__ out) {
  int b = threadIdx.x;
  if (b < 128) out[b] = 1.f / (1.f + __expf(-(logits[b] * (1.f / FF) + bc[0])));
}

// --- launch -----------------------------------------------------------------
extern "C" void kernel_launch(void* const* d_in, const int* in_sizes, int n_in,
                              void* d_out, int out_size, void* d_ws, size_t ws_size,
                              hipStream_t stream) {
  const float* x   = (const float*)d_in[0];
  const float* tp  = (const float*)d_in[1];
  const float* W1  = (const float*)d_in[2];
  const float* b1  = (const float*)d_in[3];
  const float* W2  = (const float*)d_in[4];
  const float* b2  = (const float*)d_in[5];
  const float* Wih = (const float*)d_in[6];
  const float* Whh = (const float*)d_in[7];
  const float* bih = (const float*)d_in[8];
  const float* bhh = (const float*)d_in[9];
  const float* Wc  = (const float*)d_in[10];
  const float* bc  = (const float*)d_in[11];
  float* out = (float*)d_out;

  unsigned short* W1p  = (unsigned short*)d_ws;
  unsigned short* W2p  = W1p + (size_t)HD * HD;
  unsigned short* Whhp = W2p + (size_t)HD * HD;
  unsigned short* Wihp = Whhp + (size_t)HD * HD;
  unsigned short* actg = Wihp + (size_t)HD * ID;           // G*2*S*512 bf16
  unsigned int*   ctl  = (unsigned int*)(actg + (size_t)G * 2 * S * 512);
  float*          logits = (float*)(ctl + CT_WORDS);
  // total ws use ~1.8 MB

  pack_kernel<<<(HD * HD + 255) / 256, 256, 0, stream>>>(W1, W1p, HD);
  pack_kernel<<<(HD * HD + 255) / 256, 256, 0, stream>>>(W2, W2p, HD);
  pack_kernel<<<(HD * HD + 255) / 256, 256, 0, stream>>>(Whh, Whhp, HD);
  pack_kernel<<<(HD * ID + 255) / 256, 256, 0, stream>>>(Wih, Wihp, ID);
  int nz = CT_WORDS + 128;  // ctl + logits
  zero_kernel<<<(nz + 255) / 256, 256, 0, stream>>>(ctl, nz);

  seq_kernel<<<dim3(NLAUNCH), dim3(256), 0, stream>>>(
      x, tp, b1, b2, bih, bhh, Wc, W1p, W2p, Whhp, Wihp, actg, ctl, logits);
  fin_kernel<<<dim3(1), dim3(128), 0, stream>>>(logits, bc, out);
}

// Round 9
// 4780.725 us; speedup vs baseline: 1.3191x; 1.2810x over previous
//
// ODE-RNN (B=128, F=512, I=128, H=512, O=1) on MI355X — Round 9.
// R6/R7/R8 all ~5.3-6.3 ms across 3 different flag mechanisms => the wall is
// the STAGE STRUCTURE (3 syncs + LDS gather + LDS-fed MFMA), not signaling.
// R9 deletes the gather: producers store their D-tiles directly in the
// consumer's MFMA B-fragment order (still 2x256B contiguous per wave), so
// consumers feed MFMA straight from coalesced 16B L2 loads. One sync/stage;
// waves poll & proceed independently. x is pre-packed to frag-order bf16
// (no per-f fp32 staging); the RNN x@Wih part runs between signal and wait.
// 16-MFMA chains split into two 8-chains (dependency stall /2).
// Exchange protocol (same-XCD cohorts, vmcnt-drain-before-signal, plain
// volatile flags + buffer_inv) is verbatim R8 (proven exact).
// Predicted: 2.4-3.4 ms; LDS conflicts ~0; absmax ~0.

#include <hip/hip_runtime.h>
#include <hip/hip_bf16.h>
#include <cstdint>
#include <cstddef>

#define HD 512
#define ID 128
#define FF 512
#define G 4          // groups (each owns 32 samples)
#define S 32         // samples per group
#define NBLK 16      // blocks per group (32-col weight shards)
#define NLAUNCH 256  // blocks launched (>= 9 complete cohorts by pigeonhole)

// ctl word offsets (all zeroed before seq_kernel)
#define CT_TICKET 0          // [16] per-XCD ticket counters
#define CT_CLAIM 16          // group claim counter
#define CT_TOTAL 17          // registered-block counter
#define CT_MAP 20            // [256] cohort -> group+1 (0 = unclaimed)
#define CT_PFLAG 512         // [G*64] per-producer stage flags, 256B/group
#define CT_WORDS (512 + G * 64)

#define XFRAG_ELEMS ((size_t)FF * 8 * 4 * 64 * 8)   // 8,388,608 bf16

typedef __bf16 bf16x8_t __attribute__((ext_vector_type(8)));
typedef unsigned short ushort8_t __attribute__((ext_vector_type(8)));
typedef unsigned short ushort4_t __attribute__((ext_vector_type(4)));
typedef float f32x4_t __attribute__((ext_vector_type(4)));

__device__ __forceinline__ unsigned short f2b(float x) {
  __hip_bfloat16 h = __float2bfloat16(x);
  return *reinterpret_cast<unsigned short*>(&h);
}
__device__ __forceinline__ bf16x8_t ld_frag(const unsigned short* p) {
  ushort8_t u = *reinterpret_cast<const ushort8_t*>(p);
  return __builtin_bit_cast(bf16x8_t, u);
}

// --- fp32 -> bf16 fragment-order weight pack (same layout as R3-R8) --------
// dst[i]: i = ((colt*KT + kt)*64 + lane)*8 + j, KT = Kd/32.
// lane = n + 16*kq holds W[colt*16+n][kt*32 + kq*8 + j].
__global__ void pack_kernel(const float* __restrict__ in,
                            unsigned short* __restrict__ out, int Kd) {
  int i = blockIdx.x * blockDim.x + threadIdx.x;
  int total = HD * Kd;
  if (i >= total) return;
  int KT = Kd >> 5;
  int j = i & 7;
  int lane = (i >> 3) & 63;
  int t = i >> 9;
  int kt = t % KT;
  int colt = t / KT;
  int n = lane & 15, kq = lane >> 4;
  out[i] = f2b(in[(size_t)(colt * 16 + n) * Kd + kt * 32 + kq * 8 + j]);
}

// --- x -> bf16 B-fragment order: xf[f][st=b>>4][kt<4][lane=n+16kq][8] ------
__global__ void xpack_kernel(const float* __restrict__ in,
                             unsigned short* __restrict__ out) {
  size_t i = (size_t)blockIdx.x * blockDim.x + threadIdx.x;
  if (i >= XFRAG_ELEMS) return;
  int e = (int)(i & 7);
  int lane = (int)((i >> 3) & 63);
  int kt = (int)((i >> 9) & 3);
  int st = (int)((i >> 11) & 7);
  int f = (int)(i >> 14);
  int n = lane & 15, kq = lane >> 4;
  int b = st * 16 + n;
  int ii = kt * 32 + kq * 8 + e;
  out[i] = f2b(in[((size_t)b * FF + f) * ID + ii]);
}

__global__ void zero_kernel(unsigned int* __restrict__ p, int n) {
  int i = blockIdx.x * blockDim.x + threadIdx.x;
  if (i < n) p[i] = 0u;
}

// Two interleaved 8-chains over kt=0..15; acc-in carried on even chain.
// base: ushort8 array over [32 rows][64 lanes]; rows = rt*16 + kt.
__device__ __forceinline__ f32x4_t mm16g(const bf16x8_t* wf,
                                         const ushort8_t* base, int row0,
                                         int lane, f32x4_t acc) {
  f32x4_t acc1 = {0.f, 0.f, 0.f, 0.f};
#pragma unroll
  for (int kt = 0; kt < 16; kt += 2) {
    bf16x8_t a0 = __builtin_bit_cast(bf16x8_t, base[(row0 + kt) * 64 + lane]);
    bf16x8_t a1 = __builtin_bit_cast(bf16x8_t, base[(row0 + kt + 1) * 64 + lane]);
    acc  = __builtin_amdgcn_mfma_f32_16x16x32_bf16(wf[kt], a0, acc, 0, 0, 0);
    acc1 = __builtin_amdgcn_mfma_f32_16x16x32_bf16(wf[kt + 1], a1, acc1, 0, 0, 0);
  }
  acc[0] += acc1[0]; acc[1] += acc1[1]; acc[2] += acc1[2]; acc[3] += acc1[3];
  return acc;
}

// --- the sequential recurrence ---------------------------------------------
__global__ __launch_bounds__(256, 1) void seq_kernel(
    const float* __restrict__ tp,
    const float* __restrict__ b1, const float* __restrict__ b2,
    const float* __restrict__ bih, const float* __restrict__ bhh,
    const float* __restrict__ Wc,
    const unsigned short* __restrict__ W1p, const unsigned short* __restrict__ W2p,
    const unsigned short* __restrict__ Whhp, const unsigned short* __restrict__ Wihp,
    const unsigned short* __restrict__ xf,
    unsigned short* __restrict__ actg,   // G * 2 * S*512 bf16, frag order
    unsigned int* __restrict__ ctl,      // control words (see CT_*)
    float* __restrict__ logits) {        // 128 fp32, pre-zeroed
  __shared__ float scale[S];     // dt per sample
  __shared__ float redl[S][2];
  __shared__ int role[2];

  const int tid = threadIdx.x;

  // ---- XCD-aware registration & group claiming (tid 0 only; R5-R8 proven) --
  if (tid == 0) {
    unsigned xcc;
    asm volatile("s_getreg_b32 %0, hwreg(HW_REG_XCC_ID, 0, 32)" : "=s"(xcc));
    const int xcd = (int)(xcc & 15u);
    unsigned rank = __hip_atomic_fetch_add(&ctl[CT_TICKET + xcd], 1u,
                                           __ATOMIC_RELAXED,
                                           __HIP_MEMORY_SCOPE_AGENT);
    const unsigned slot = (unsigned)xcd * 16u + (rank >> 4);
    if ((rank & 15u) == 15u) {  // cohort completer claims a group id
      unsigned gg = __hip_atomic_fetch_add(&ctl[CT_CLAIM], 1u,
                                           __ATOMIC_RELAXED,
                                           __HIP_MEMORY_SCOPE_AGENT);
      __hip_atomic_store(&ctl[CT_MAP + slot], gg + 1u, __ATOMIC_RELAXED,
                         __HIP_MEMORY_SCOPE_AGENT);
      asm volatile("s_waitcnt vmcnt(0)" ::: "memory");  // publish before total
    }
    __hip_atomic_fetch_add(&ctl[CT_TOTAL], 1u, __ATOMIC_RELAXED,
                           __HIP_MEMORY_SCOPE_AGENT);
    unsigned m;
    for (;;) {
      m = __hip_atomic_load(&ctl[CT_MAP + slot], __ATOMIC_RELAXED,
                            __HIP_MEMORY_SCOPE_AGENT);
      if (m) break;
      if (__hip_atomic_load(&ctl[CT_TOTAL], __ATOMIC_RELAXED,
                            __HIP_MEMORY_SCOPE_AGENT) >= (unsigned)NLAUNCH) {
        m = __hip_atomic_load(&ctl[CT_MAP + slot], __ATOMIC_RELAXED,
                              __HIP_MEMORY_SCOPE_AGENT);
        break;
      }
      __builtin_amdgcn_s_sleep(2);
    }
    role[0] = (m == 0 || m > (unsigned)G) ? -1 : (int)(m - 1);
    role[1] = (int)(rank & 15u);
  }
  __syncthreads();
  if (role[0] < 0) return;   // surplus / incomplete cohort: exit
  const int g = role[0];     // group id 0..3  (samples [g*32, g*32+32))
  const int j = role[1];     // 32-col weight shard 0..15

  const int wave = tid >> 6;
  const int lane = tid & 63;
  const int n = lane & 15;
  const int kq = lane >> 4;
  const int ct = wave & 1;         // col-tile within shard
  const int rt = wave >> 1;        // row-tile (samples)
  const int colt = j * 2 + ct;     // global 16-col tile
  const int sl2 = rt * 16 + n;     // this lane's sample (D col = lane&15)
  const int gc0 = j * 32 + ct * 16 + kq * 4;  // lane's 4-col base (D rows)
  const int s0 = g * S;

  // ---- weights into registers ----
  bf16x8_t w1f[16], w2f[16], whhf[16], wihf[4];
#pragma unroll
  for (int kt = 0; kt < 16; ++kt) {
    w1f[kt]  = ld_frag(W1p  + (size_t)(colt * 16 + kt) * 512 + lane * 8);
    w2f[kt]  = ld_frag(W2p  + (size_t)(colt * 16 + kt) * 512 + lane * 8);
    whhf[kt] = ld_frag(Whhp + (size_t)(colt * 16 + kt) * 512 + lane * 8);
  }
#pragma unroll
  for (int kt = 0; kt < 4; ++kt)
    wihf[kt] = ld_frag(Wihp + (size_t)(colt * 4 + kt) * 512 + lane * 8);

  const f32x4_t b1v = *reinterpret_cast<const f32x4_t*>(&b1[gc0]);
  const f32x4_t b2v = *reinterpret_cast<const f32x4_t*>(&b2[gc0]);
  f32x4_t bbv;
#pragma unroll
  for (int r_ = 0; r_ < 4; ++r_) bbv[r_] = bih[gc0 + r_] + bhh[gc0 + r_];
  f32x4_t hv = {0.f, 0.f, 0.f, 0.f};   // fp32 master h (lane-private)
  f32x4_t fsv = {0.f, 0.f, 0.f, 0.f};  // sum of post-RNN h (lane-private)

  unsigned short* const myact = actg + (size_t)g * (2 * S * 512);
  unsigned int* const pf = &ctl[CT_PFLAG + g * 64];  // 16 words, own 256B
  int bar = 0;

  // Producer store offset (elems) in consumer B-frag order:
  // value for (sample rt*16+n, col 32j+16ct+4kq+r) lands at
  // row (rt*16 + j), lane' = n + 16*(2ct + kq/2), elem (kq&1)*4 + r.
  const size_t soff =
      ((size_t)(rt * 16 + j) * 64 + n + 16 * (2 * ct + (kq >> 1))) * 8 +
      (kq & 1) * 4;
  const int row0 = rt * 16;

  asm volatile("buffer_inv" ::: "memory");   // drop any pre-kernel L1 lines
  asm volatile("s_waitcnt vmcnt(0)" ::: "memory");

  // signal: all producer stores of this block are in the local L2 before the
  // (plain, write-through) flag store can be issued.
  auto signal = [&]() {
    asm volatile("s_waitcnt vmcnt(0)" ::: "memory");
    __syncthreads();
    if (tid == 0)
      *(volatile unsigned int*)(pf + j) = (unsigned)(bar + 1);
  };
  // wait: every wave independently polls all 16 flags (one local-L2 line);
  // its own final buffer_inv precedes its frag loads (no stale L1).
  auto wait_ = [&]() {
    const unsigned want = (unsigned)(bar + 1);
    for (;;) {
      asm volatile("buffer_inv" ::: "memory");
      unsigned v = *(volatile const unsigned int*)(pf + (lane & 15));
      if (__ballot(v < want) == 0ull) break;
    }
    ++bar;
  };

#pragma unroll 1
  for (int f = 0; f < FF; ++f) {
    // dt per sample (wave0; published by the sync inside signal() of stage A)
    if (tid < S) {
      float d = (f > 0) ? (tp[(size_t)(s0 + tid) * FF + f] -
                           tp[(size_t)(s0 + tid) * FF + f - 1])
                        : 0.f;
      scale[tid] = d;
    }

    // ---- A: g1 = relu(h @ W1^T + b1) ----
    {
      const ushort8_t* src =
          (const ushort8_t*)(myact + (size_t)((bar & 1) ^ 1) * (S * 512));
      f32x4_t acc = {0.f, 0.f, 0.f, 0.f};
      acc = mm16g(w1f, src, row0, lane, acc);
      unsigned short* dst = myact + (size_t)(bar & 1) * (S * 512);
      ushort4_t o;
#pragma unroll
      for (int r_ = 0; r_ < 4; ++r_) {
        float y = acc[r_] + b1v[r_];
        o[r_] = f2b(y > 0.f ? y : 0.f);
      }
      *reinterpret_cast<ushort4_t*>(dst + soff) = o;
      signal(); wait_();
    }
    // ---- B: k1 = g1 @ W2^T + b2; publish h+0.8dt k1; hv += 0.5dt k1 ----
    {
      const ushort8_t* src =
          (const ushort8_t*)(myact + (size_t)((bar & 1) ^ 1) * (S * 512));
      f32x4_t acc = {0.f, 0.f, 0.f, 0.f};
      acc = mm16g(w2f, src, row0, lane, acc);
      unsigned short* dst = myact + (size_t)(bar & 1) * (S * 512);
      const float d = scale[sl2];
      ushort4_t o;
#pragma unroll
      for (int r_ = 0; r_ < 4; ++r_) {
        float k1 = acc[r_] + b2v[r_];
        float ho = hv[r_];
        o[r_] = f2b(ho + 0.8f * d * k1);
        hv[r_] = ho + 0.5f * d * k1;
      }
      *reinterpret_cast<ushort4_t*>(dst + soff) = o;
      signal(); wait_();
    }
    // ---- C: g2 = relu(h2 @ W1^T + b1) ----
    {
      const ushort8_t* src =
          (const ushort8_t*)(myact + (size_t)((bar & 1) ^ 1) * (S * 512));
      f32x4_t acc = {0.f, 0.f, 0.f, 0.f};
      acc = mm16g(w1f, src, row0, lane, acc);
      unsigned short* dst = myact + (size_t)(bar & 1) * (S * 512);
      ushort4_t o;
#pragma unroll
      for (int r_ = 0; r_ < 4; ++r_) {
        float y = acc[r_] + b1v[r_];
        o[r_] = f2b(y > 0.f ? y : 0.f);
      }
      *reinterpret_cast<ushort4_t*>(dst + soff) = o;
      signal(); wait_();
    }
    // ---- D: k2 = g2 @ W2^T + b2; h' = hv + 0.5dt k2; publish h' ----
    f32x4_t accx;
    {
      const ushort8_t* src =
          (const ushort8_t*)(myact + (size_t)((bar & 1) ^ 1) * (S * 512));
      f32x4_t acc = {0.f, 0.f, 0.f, 0.f};
      acc = mm16g(w2f, src, row0, lane, acc);
      unsigned short* dst = myact + (size_t)(bar & 1) * (S * 512);
      const float d = scale[sl2];
      ushort4_t o;
#pragma unroll
      for (int r_ = 0; r_ < 4; ++r_) {
        float h = hv[r_] + 0.5f * d * (acc[r_] + b2v[r_]);
        hv[r_] = h;
        o[r_] = f2b(h);
      }
      *reinterpret_cast<ushort4_t*>(dst + soff) = o;
      signal();
      // x @ Wih^T between signal and wait: overlaps poll latency, no
      // dependence on the exchange.
      const ushort8_t* xsrc =
          (const ushort8_t*)xf + (size_t)((f * 8 + g * 2 + rt) * 4) * 64;
      accx = (f32x4_t){0.f, 0.f, 0.f, 0.f};
#pragma unroll
      for (int kt = 0; kt < 4; ++kt) {
        bf16x8_t a = __builtin_bit_cast(bf16x8_t, xsrc[kt * 64 + lane]);
        accx = __builtin_amdgcn_mfma_f32_16x16x32_bf16(wihf[kt], a, accx,
                                                       0, 0, 0);
      }
      wait_();
    }
    // ---- RNN: h = tanh(x@Wih^T + h' @ Whh^T + bih + bhh) ----
    {
      const ushort8_t* src =
          (const ushort8_t*)(myact + (size_t)((bar & 1) ^ 1) * (S * 512));
      f32x4_t acc = mm16g(whhf, src, row0, lane, accx);
      unsigned short* dst = myact + (size_t)(bar & 1) * (S * 512);
      ushort4_t o;
#pragma unroll
      for (int r_ = 0; r_ < 4; ++r_) {
        float t = tanhf(acc[r_] + bbv[r_]);
        hv[r_] = t;
        fsv[r_] += t;
        o[r_] = f2b(t);
      }
      *reinterpret_cast<ushort4_t*>(dst + soff) = o;
      signal(); wait_();
    }
  }

  // ---- classifier: logits[s] += sum over this block's 32 cols ----
  {
    float p = fsv[0] * Wc[gc0] + fsv[1] * Wc[gc0 + 1] +
              fsv[2] * Wc[gc0 + 2] + fsv[3] * Wc[gc0 + 3];
    p += __shfl_xor(p, 16, 64);   // reduce over kq
    p += __shfl_xor(p, 32, 64);
    if (lane < 16) redl[rt * 16 + lane][ct] = p;
  }
  __syncthreads();
  if (tid < S) {
    float v = redl[tid][0] + redl[tid][1];
    atomicAdd(&logits[s0 + tid], v);   // device-scope, cross-XCD safe
  }
}

__global__ void fin_kernel(const float* __restrict__ logits,
                           const float* __restrict__ bc,
                           float* __restrict__ out) {
  int b = threadIdx.x;
  if (b < 128) out[b] = 1.f / (1.f + __expf(-(logits[b] * (1.f / FF) + bc[0])));
}

// --- launch -----------------------------------------------------------------
extern "C" void kernel_launch(void* const* d_in, const int* in_sizes, int n_in,
                              void* d_out, int out_size, void* d_ws, size_t ws_size,
                              hipStream_t stream) {
  const float* x   = (const float*)d_in[0];
  const float* tp  = (const float*)d_in[1];
  const float* W1  = (const float*)d_in[2];
  const float* b1  = (const float*)d_in[3];
  const float* W2  = (const float*)d_in[4];
  const float* b2  = (const float*)d_in[5];
  const float* Wih = (const float*)d_in[6];
  const float* Whh = (const float*)d_in[7];
  const float* bih = (const float*)d_in[8];
  const float* bhh = (const float*)d_in[9];
  const float* Wc  = (const float*)d_in[10];
  const float* bc  = (const float*)d_in[11];
  float* out = (float*)d_out;

  unsigned short* W1p  = (unsigned short*)d_ws;
  unsigned short* W2p  = W1p + (size_t)HD * HD;
  unsigned short* Whhp = W2p + (size_t)HD * HD;
  unsigned short* Wihp = Whhp + (size_t)HD * HD;
  unsigned short* xfp  = Wihp + (size_t)HD * ID;
  unsigned short* actg = xfp + XFRAG_ELEMS;                // G*2*S*512 bf16
  unsigned int*   ctl  = (unsigned int*)(actg + (size_t)G * 2 * S * 512);
  float*          logits = (float*)(ctl + CT_WORDS);
  // total ws use ~18.8 MB

  pack_kernel<<<(HD * HD + 255) / 256, 256, 0, stream>>>(W1, W1p, HD);
  pack_kernel<<<(HD * HD + 255) / 256, 256, 0, stream>>>(W2, W2p, HD);
  pack_kernel<<<(HD * HD + 255) / 256, 256, 0, stream>>>(Whh, Whhp, HD);
  pack_kernel<<<(HD * ID + 255) / 256, 256, 0, stream>>>(Wih, Wihp, ID);
  xpack_kernel<<<(int)((XFRAG_ELEMS + 255) / 256), 256, 0, stream>>>(x, xfp);
  // zero actg (h0 = 0 read at f=0) + ctl + logits (contiguous)
  int nz = (int)(G * 2 * S * 512 / 2) + CT_WORDS + 128;
  zero_kernel<<<(nz + 255) / 256, 256, 0, stream>>>((unsigned int*)actg, nz);

  seq_kernel<<<dim3(NLAUNCH), dim3(256), 0, stream>>>(
      tp, b1, b2, bih, bhh, Wc, W1p, W2p, Whhp, Wihp, xfp, actg, ctl, logits);
  fin_kernel<<<dim3(1), dim3(128), 0, stream>>>(logits, bc, out);
}